// Round 3
// baseline (926.690 us; speedup 1.0000x reference)
//
#include <hip/hip_runtime.h>

typedef unsigned short u16;
typedef __bf16 bf16x8 __attribute__((ext_vector_type(8)));
typedef float f32x4 __attribute__((ext_vector_type(4)));
typedef u16 u16x8 __attribute__((ext_vector_type(8)));

constexpr int T_DIM = 4096;
constexpr int DH    = 256;

__device__ __forceinline__ u16 f2bf(float f) {
    union { float f; unsigned u; } v; v.f = f;
    return (u16)((v.u + 0x7FFFu + ((v.u >> 16) & 1u)) >> 16);
}

// ---------------- prep: Wt[j][k] = bf16(W[k][j]) ----------------
__global__ __launch_bounds__(256) void prep_w(
    const float* __restrict__ Wq, const float* __restrict__ Wk,
    const float* __restrict__ Wv, const float* __restrict__ Wo,
    u16* __restrict__ Wqt, u16* __restrict__ Wkt,
    u16* __restrict__ Wvt, u16* __restrict__ Wot)
{
    int idx = blockIdx.x * 256 + threadIdx.x;
    int j = idx >> 8, k = idx & 255;
    int s = k * 256 + j;
    Wqt[idx] = f2bf(Wq[s]);
    Wkt[idx] = f2bf(Wk[s]);
    Wvt[idx] = f2bf(Wv[s]);
    Wot[idx] = f2bf(Wo[s]);
}

// ---------------- QKV projection: 64 rows/block, 4 waves ----------------
__global__ __launch_bounds__(256) void qkv_kernel(
    const float* __restrict__ x,
    const u16* __restrict__ Wqt, const u16* __restrict__ Wkt, const u16* __restrict__ Wvt,
    const float* __restrict__ bq, const float* __restrict__ bk, const float* __restrict__ bv,
    u16* __restrict__ Qg, u16* __restrict__ Kg, u16* __restrict__ Vtg)
{
    __shared__ u16 xlds[64 * DH];
    char* xl = (char*)xlds;
    const int tid = threadIdx.x;
    const long row0 = (long)blockIdx.x * 64;

    #pragma unroll
    for (int i = 0; i < 8; ++i) {
        int sid  = tid + i * 256;
        int row  = sid >> 5;
        int slot = sid & 31;
        const float* src = x + (row0 + row) * DH + slot * 8;
        float4 a  = *(const float4*)(src);
        float4 b2 = *(const float4*)(src + 4);
        u16x8 p;
        p[0] = f2bf(a.x);  p[1] = f2bf(a.y);  p[2] = f2bf(a.z);  p[3] = f2bf(a.w);
        p[4] = f2bf(b2.x); p[5] = f2bf(b2.y); p[6] = f2bf(b2.z); p[7] = f2bf(b2.w);
        *(u16x8*)(xl + row * 512 + ((slot * 16) ^ ((row & 7) << 4))) = p;
    }
    __syncthreads();

    const int w = tid >> 6, l = tid & 63;
    const int lr = l & 15, lh = l >> 4;
    const int arow = w * 16 + lr;

    bf16x8 af[8];
    #pragma unroll
    for (int ks = 0; ks < 8; ++ks)
        af[ks] = *(const bf16x8*)(xl + arow * 512 + ((ks * 64 + lh * 16) ^ ((arow & 7) << 4)));

    const u16*  Wt3[3] = { Wqt, Wkt, Wvt };
    const float* b3[3] = { bq, bk, bv };

    #pragma unroll
    for (int tgt = 0; tgt < 3; ++tgt) {
        f32x4 acc[16] = {};
        const u16* Wt = Wt3[tgt];
        #pragma unroll
        for (int ks = 0; ks < 8; ++ks) {
            bf16x8 a = af[ks];
            #pragma unroll
            for (int n = 0; n < 16; ++n) {
                bf16x8 bf = *(const bf16x8*)(Wt + (n * 16 + lr) * DH + ks * 32 + lh * 8);
                acc[n] = __builtin_amdgcn_mfma_f32_16x16x32_bf16(a, bf, acc[n], 0, 0, 0);
            }
        }
        const float* bias = b3[tgt];
        long grow = row0 + w * 16 + lh * 4;
        #pragma unroll
        for (int n = 0; n < 16; ++n) {
            int col = n * 16 + lr;
            float bb = bias[col];
            #pragma unroll
            for (int r = 0; r < 4; ++r) {
                u16 h = f2bf(acc[n][r] + bb);
                long g = grow + r;
                if (tgt == 0)      Qg[g * DH + col] = h;
                else if (tgt == 1) Kg[g * DH + col] = h;
                else {
                    long bb2 = g >> 12;
                    int  tt  = (int)(g & 4095);
                    Vtg[(bb2 * DH + col) * T_DIM + tt] = h;
                }
            }
        }
    }
}

// ---- fused retention: 128 q-rows/block, 8 waves = 2 s-groups x 4 waves x 32 rows ----
__global__ __launch_bounds__(512) void retention_kernel(
    const u16* __restrict__ Qg, const u16* __restrict__ Kg, const u16* __restrict__ Vtg,
    const float* __restrict__ gamma, u16* __restrict__ Rg)
{
    __shared__ u16 lds[65536];          // 128KB: [2 groups][K 32KB] + [2 groups][Vt 32KB]
    char* base = (char*)lds;
    const int tid = threadIdx.x;
    const int w = tid >> 6, l = tid & 63;
    const int lr = l & 15, lh = l >> 4;
    const int g  = w >> 2, wq = w & 3;            // s-group, q-wave within group
    const int b  = blockIdx.x >> 5;
    const int q0 = (blockIdx.x & 31) * 128;
    const int tl = tid & 255;

    char* kl = base + g * 32768;                  // this group's K tile
    char* vl = base + 65536 + g * 32768;          // this group's Vt tile
    char* pb = kl + wq * 4096;                    // this wave's P area (in K region)

    // Q A-frags for the wave's 32 rows (2 row-groups x 16)
    bf16x8 qf[2][8];
    #pragma unroll
    for (int rg = 0; rg < 2; ++rg) {
        const char* qb = (const char*)(Qg + ((long)b * T_DIM + q0 + wq * 32 + rg * 16 + lr) * DH);
        #pragma unroll
        for (int ks = 0; ks < 8; ++ks)
            qf[rg][ks] = *(const bf16x8*)(qb + ks * 64 + lh * 16);
    }

    f32x4 acc[2][16] = {};                        // 32 rows x 256 cols partials

    for (int it = 0; it < 32; ++it) {
        const int s0 = it * 128 + g * 64;         // group-interleaved s-tiles
        __syncthreads();                          // prev-iter P/Vt reads done

        {   // stage K tile [64][256] bf16, swizzled (group-private)
            const char* kg = (const char*)(Kg + ((long)b * T_DIM + s0) * DH);
            #pragma unroll
            for (int i = 0; i < 8; ++i) {
                int sid = tl + i * 256;
                int row = sid >> 5, slot = sid & 31;
                u16x8 v = *(const u16x8*)(kg + row * 512 + slot * 16);
                *(u16x8*)(kl + row * 512 + ((slot * 16) ^ ((row & 7) << 4))) = v;
            }
        }
        {   // stage Vt tile [256][64] bf16, swizzled (group-private)
            const char* vg = (const char*)(Vtg + (long)b * DH * T_DIM + s0);
            #pragma unroll
            for (int i = 0; i < 8; ++i) {
                int sid = tl + i * 256;
                int row = sid >> 3, slot = sid & 7;
                u16x8 v = *(const u16x8*)(vg + (long)row * (T_DIM * 2) + slot * 16);
                *(u16x8*)(vl + row * 128 + ((slot * 16) ^ ((row & 7) << 4))) = v;
            }
        }
        __syncthreads();

        // S = Q K^T for 32 rows x 64 s; gate with gamma; pack bf16
        u16 pv[2][4][4];
        const float* gbase = gamma + (long)(q0 + wq * 32) * T_DIM + s0;
        #pragma unroll
        for (int n = 0; n < 4; ++n) {
            f32x4 sa = {}, sb = {};
            #pragma unroll
            for (int ks = 0; ks < 8; ++ks) {
                int srow = n * 16 + lr;
                bf16x8 bf = *(const bf16x8*)(kl + srow * 512 + ((ks * 64 + lh * 16) ^ ((srow & 7) << 4)));
                sa = __builtin_amdgcn_mfma_f32_16x16x32_bf16(qf[0][ks], bf, sa, 0, 0, 0);
                sb = __builtin_amdgcn_mfma_f32_16x16x32_bf16(qf[1][ks], bf, sb, 0, 0, 0);
            }
            #pragma unroll
            for (int r = 0; r < 4; ++r) {
                float g0 = gbase[(long)(lh * 4 + r) * T_DIM + n * 16 + lr];
                float g1 = gbase[(long)(16 + lh * 4 + r) * T_DIM + n * 16 + lr];
                pv[0][n][r] = f2bf(g0 * sa[r]);
                pv[1][n][r] = f2bf(g1 * sb[r]);
            }
        }
        __syncthreads();                          // all group waves done reading K

        // write P [32][64] bf16 into this wave's K-region slot, swizzled
        #pragma unroll
        for (int rg = 0; rg < 2; ++rg)
            #pragma unroll
            for (int n = 0; n < 4; ++n) {
                int cb = (n * 16 + lr) * 2;
                #pragma unroll
                for (int r = 0; r < 4; ++r) {
                    int pr = rg * 16 + lh * 4 + r;
                    *(u16*)(pb + pr * 128 + (cb ^ ((pr & 7) << 4))) = pv[rg][n][r];
                }
            }

        // A-frags from own P (same-wave LDS, program order)
        bf16x8 pa[2][2];
        #pragma unroll
        for (int rg = 0; rg < 2; ++rg)
            #pragma unroll
            for (int k2 = 0; k2 < 2; ++k2) {
                int prr = rg * 16 + lr;
                pa[rg][k2] = *(const bf16x8*)(pb + prr * 128 + ((k2 * 64 + lh * 16) ^ ((prr & 7) << 4)));
            }

        // retained += P @ V
        #pragma unroll
        for (int n = 0; n < 16; ++n) {
            int vrow = n * 16 + lr;
            #pragma unroll
            for (int k2 = 0; k2 < 2; ++k2) {
                bf16x8 bv = *(const bf16x8*)(vl + vrow * 128 + ((k2 * 64 + lh * 16) ^ ((vrow & 7) << 4)));
                acc[0][n] = __builtin_amdgcn_mfma_f32_16x16x32_bf16(pa[0][k2], bv, acc[0][n], 0, 0, 0);
                acc[1][n] = __builtin_amdgcn_mfma_f32_16x16x32_bf16(pa[1][k2], bv, acc[1][n], 0, 0, 0);
            }
        }
    }

    // ---- cross-group reduction: group 1 dumps partials to LDS, group 0 adds + stores ----
    __syncthreads();
    if (g == 1) {
        char* eb = base + wq * 32768;             // 32 rows x 1KB
        #pragma unroll
        for (int rg = 0; rg < 2; ++rg)
            #pragma unroll
            for (int n = 0; n < 16; ++n) {
                int col = n * 16 + lr;
                #pragma unroll
                for (int r = 0; r < 4; ++r) {
                    int row = rg * 16 + lh * 4 + r;
                    *(float*)(eb + row * 1024 + ((col * 4) ^ ((row & 7) << 4))) = acc[rg][n][r];
                }
            }
    }
    __syncthreads();
    if (g == 0) {
        char* eb = base + wq * 32768;
        long grow = (long)b * T_DIM + q0 + wq * 32;
        #pragma unroll
        for (int rg = 0; rg < 2; ++rg)
            #pragma unroll
            for (int n = 0; n < 16; ++n) {
                int col = n * 16 + lr;
                #pragma unroll
                for (int r = 0; r < 4; ++r) {
                    int row = rg * 16 + lh * 4 + r;
                    float s = acc[rg][n][r] +
                              *(const float*)(eb + row * 1024 + ((col * 4) ^ ((row & 7) << 4)));
                    Rg[(grow + row) * DH + col] = f2bf(s);
                }
            }
    }
}

// ---------------- output projection + PReLU ----------------
__global__ __launch_bounds__(256) void out_kernel(
    const u16* __restrict__ Rg, const u16* __restrict__ Wot,
    const float* __restrict__ bo, const float* __restrict__ pa,
    float* __restrict__ out)
{
    __shared__ u16 rlds[64 * DH];
    char* rl = (char*)rlds;
    const int tid = threadIdx.x;
    const long row0 = (long)blockIdx.x * 64;
    #pragma unroll
    for (int i = 0; i < 8; ++i) {
        int sid = tid + i * 256;
        int row = sid >> 5, slot = sid & 31;
        u16x8 v = *(const u16x8*)((const char*)(Rg + (row0 + row) * DH) + slot * 16);
        *(u16x8*)(rl + row * 512 + ((slot * 16) ^ ((row & 7) << 4))) = v;
    }
    __syncthreads();
    const int w = tid >> 6, l = tid & 63;
    const int lr = l & 15, lh = l >> 4;
    const int arow = w * 16 + lr;
    f32x4 acc[16] = {};
    #pragma unroll
    for (int ks = 0; ks < 8; ++ks) {
        bf16x8 a = *(const bf16x8*)(rl + arow * 512 + ((ks * 64 + lh * 16) ^ ((arow & 7) << 4)));
        #pragma unroll
        for (int n = 0; n < 16; ++n) {
            bf16x8 bf = *(const bf16x8*)(Wot + (n * 16 + lr) * DH + ks * 32 + lh * 8);
            acc[n] = __builtin_amdgcn_mfma_f32_16x16x32_bf16(a, bf, acc[n], 0, 0, 0);
        }
    }
    const float alpha = pa[0];
    long grow = row0 + w * 16 + lh * 4;
    #pragma unroll
    for (int n = 0; n < 16; ++n) {
        int col = n * 16 + lr;
        float bb = bo[col];
        #pragma unroll
        for (int r = 0; r < 4; ++r) {
            float y = acc[n][r] + bb;
            out[(grow + r) * DH + col] = (y >= 0.f) ? y : alpha * y;
        }
    }
}

extern "C" void kernel_launch(void* const* d_in, const int* in_sizes, int n_in,
                              void* d_out, int out_size, void* d_ws, size_t ws_size,
                              hipStream_t stream)
{
    const float* x     = (const float*)d_in[0];
    const float* gamma = (const float*)d_in[1];
    const float* Wq = (const float*)d_in[2];
    const float* bq = (const float*)d_in[3];
    const float* Wk = (const float*)d_in[4];
    const float* bk = (const float*)d_in[5];
    const float* Wv = (const float*)d_in[6];
    const float* bv = (const float*)d_in[7];
    const float* Wo = (const float*)d_in[8];
    const float* bo = (const float*)d_in[9];
    const float* pa = (const float*)d_in[10];
    float* out = (float*)d_out;

    char* ws = (char*)d_ws;
    const long SZ = 16777216L;                 // 8*4096*256 bf16 bytes
    u16* Wqt = (u16*)(ws);
    u16* Wkt = (u16*)(ws + 131072);
    u16* Wvt = (u16*)(ws + 262144);
    u16* Wot = (u16*)(ws + 393216);
    u16* Qg  = (u16*)(ws + 524288);
    u16* Kg  = (u16*)(ws + 524288 + SZ);
    u16* Vtg = (u16*)(ws + 524288 + 2 * SZ);
    u16* Rg  = (u16*)(ws + 524288 + 3 * SZ);

    hipLaunchKernelGGL(prep_w, dim3(256), dim3(256), 0, stream,
                       Wq, Wk, Wv, Wo, Wqt, Wkt, Wvt, Wot);
    hipLaunchKernelGGL(qkv_kernel, dim3(512), dim3(256), 0, stream,
                       x, Wqt, Wkt, Wvt, bq, bk, bv, Qg, Kg, Vtg);
    hipLaunchKernelGGL(retention_kernel, dim3(256), dim3(512), 0, stream,
                       Qg, Kg, Vtg, gamma, Rg);
    hipLaunchKernelGGL(out_kernel, dim3(512), dim3(256), 0, stream,
                       Rg, Wot, bo, pa, out);
}

// Round 4
// 349.781 us; speedup vs baseline: 2.6493x; 2.6493x over previous
//
#include <hip/hip_runtime.h>

typedef unsigned short u16;
typedef __bf16 bf16x8 __attribute__((ext_vector_type(8)));
typedef float f32x4 __attribute__((ext_vector_type(4)));
typedef u16 u16x8 __attribute__((ext_vector_type(8)));

constexpr int T_DIM = 4096;
constexpr int DH    = 256;

__device__ __forceinline__ u16 f2bf(float f) {
    union { float f; unsigned u; } v; v.f = f;
    return (u16)((v.u + 0x7FFFu + ((v.u >> 16) & 1u)) >> 16);
}

// ---------------- prep: Wt[j][k] = bf16(W[k][j]) ----------------
__global__ __launch_bounds__(256) void prep_w(
    const float* __restrict__ Wq, const float* __restrict__ Wk,
    const float* __restrict__ Wv, const float* __restrict__ Wo,
    u16* __restrict__ Wqt, u16* __restrict__ Wkt,
    u16* __restrict__ Wvt, u16* __restrict__ Wot)
{
    int idx = blockIdx.x * 256 + threadIdx.x;
    int j = idx >> 8, k = idx & 255;
    int s = k * 256 + j;
    Wqt[idx] = f2bf(Wq[s]);
    Wkt[idx] = f2bf(Wk[s]);
    Wvt[idx] = f2bf(Wv[s]);
    Wot[idx] = f2bf(Wo[s]);
}

// ---------------- QKV projection: 64 rows/block, 4 waves ----------------
__global__ __launch_bounds__(256) void qkv_kernel(
    const float* __restrict__ x,
    const u16* __restrict__ Wqt, const u16* __restrict__ Wkt, const u16* __restrict__ Wvt,
    const float* __restrict__ bq, const float* __restrict__ bk, const float* __restrict__ bv,
    u16* __restrict__ Qg, u16* __restrict__ Kg, u16* __restrict__ Vtg)
{
    __shared__ u16 xlds[64 * DH];
    char* xl = (char*)xlds;
    const int tid = threadIdx.x;
    const long row0 = (long)blockIdx.x * 64;

    #pragma unroll
    for (int i = 0; i < 8; ++i) {
        int sid  = tid + i * 256;
        int row  = sid >> 5;
        int slot = sid & 31;
        const float* src = x + (row0 + row) * DH + slot * 8;
        float4 a  = *(const float4*)(src);
        float4 b2 = *(const float4*)(src + 4);
        u16x8 p;
        p[0] = f2bf(a.x);  p[1] = f2bf(a.y);  p[2] = f2bf(a.z);  p[3] = f2bf(a.w);
        p[4] = f2bf(b2.x); p[5] = f2bf(b2.y); p[6] = f2bf(b2.z); p[7] = f2bf(b2.w);
        *(u16x8*)(xl + row * 512 + ((slot * 16) ^ ((row & 7) << 4))) = p;
    }
    __syncthreads();

    const int w = tid >> 6, l = tid & 63;
    const int lr = l & 15, lh = l >> 4;
    const int arow = w * 16 + lr;

    bf16x8 af[8];
    #pragma unroll
    for (int ks = 0; ks < 8; ++ks)
        af[ks] = *(const bf16x8*)(xl + arow * 512 + ((ks * 64 + lh * 16) ^ ((arow & 7) << 4)));

    const u16*  Wt3[3] = { Wqt, Wkt, Wvt };
    const float* b3[3] = { bq, bk, bv };

    #pragma unroll
    for (int tgt = 0; tgt < 3; ++tgt) {
        f32x4 acc[16] = {};
        const u16* Wt = Wt3[tgt];
        #pragma unroll
        for (int ks = 0; ks < 8; ++ks) {
            bf16x8 a = af[ks];
            #pragma unroll
            for (int n = 0; n < 16; ++n) {
                bf16x8 bf = *(const bf16x8*)(Wt + (n * 16 + lr) * DH + ks * 32 + lh * 8);
                acc[n] = __builtin_amdgcn_mfma_f32_16x16x32_bf16(a, bf, acc[n], 0, 0, 0);
            }
        }
        const float* bias = b3[tgt];
        long grow = row0 + w * 16 + lh * 4;
        #pragma unroll
        for (int n = 0; n < 16; ++n) {
            int col = n * 16 + lr;
            float bb = bias[col];
            #pragma unroll
            for (int r = 0; r < 4; ++r) {
                u16 h = f2bf(acc[n][r] + bb);
                long g = grow + r;
                if (tgt == 0)      Qg[g * DH + col] = h;
                else if (tgt == 1) Kg[g * DH + col] = h;
                else {
                    long bb2 = g >> 12;
                    int  tt  = (int)(g & 4095);
                    Vtg[(bb2 * DH + col) * T_DIM + tt] = h;
                }
            }
        }
    }
}

// ---- fused retention: 128 q-rows/block, 8 waves = 4 q-chunks x 2 d-halves ----
__global__ __launch_bounds__(512, 2) void retention_kernel(
    const u16* __restrict__ Qg, const u16* __restrict__ Kg, const u16* __restrict__ Vtg,
    const float* __restrict__ gamma, u16* __restrict__ Rg)
{
    __shared__ __align__(16) char lds[81920];     // K 32KB | Vt 32KB | P 16KB
    char* kl = lds;
    char* vl = lds + 32768;
    char* pl = lds + 65536;
    const int tid = threadIdx.x;
    const int w = tid >> 6, l = tid & 63;
    const int lr = l & 15, lh = l >> 4;
    const int wq = w >> 1, dh = w & 1;            // q-chunk (32 rows), d-half (128 cols)
    const int b  = blockIdx.x >> 5;
    const int q0 = (blockIdx.x & 31) * 128;

    // Q A-frags for the wave's 32 rows (2 row-groups x 16); persistent 64 VGPRs
    bf16x8 qf[2][8];
    #pragma unroll
    for (int rg = 0; rg < 2; ++rg) {
        const char* qb = (const char*)(Qg + ((long)b * T_DIM + q0 + wq * 32 + rg * 16 + lr) * DH);
        #pragma unroll
        for (int ks = 0; ks < 8; ++ks)
            qf[rg][ks] = *(const bf16x8*)(qb + ks * 64 + lh * 16);
    }

    f32x4 acc[2][8] = {};                         // 32 rows x 128 cols -> 64 VGPRs

    for (int it = 0; it < 64; ++it) {
        const int s0 = it * 64;
        __syncthreads();                          // prev-iter P/Vt reads done

        {   // stage K tile [64][256] bf16, swizzled
            const char* kg = (const char*)(Kg + ((long)b * T_DIM + s0) * DH);
            #pragma unroll
            for (int i = 0; i < 4; ++i) {
                int sid = tid + i * 512;
                int row = sid >> 5, slot = sid & 31;
                u16x8 v = *(const u16x8*)(kg + row * 512 + slot * 16);
                *(u16x8*)(kl + row * 512 + ((slot * 16) ^ ((row & 7) << 4))) = v;
            }
        }
        {   // stage Vt tile [256][64] bf16, swizzled (128B rows)
            const char* vg = (const char*)(Vtg + (long)b * DH * T_DIM + s0);
            #pragma unroll
            for (int i = 0; i < 4; ++i) {
                int sid = tid + i * 512;
                int row = sid >> 3, slot = sid & 7;
                u16x8 v = *(const u16x8*)(vg + (long)row * (T_DIM * 2) + slot * 16);
                *(u16x8*)(vl + row * 128 + ((slot * 16) ^ ((row & 7) << 4))) = v;
            }
        }
        __syncthreads();

        // QK^T: 32 q-rows x 32 s-cols (this wave's dh half), gate, pack, write P
        const float* gbase = gamma + (long)(q0 + wq * 32) * T_DIM + s0 + dh * 32;
        #pragma unroll
        for (int n = 0; n < 2; ++n) {
            f32x4 sa = {}, sb = {};
            const int srow = dh * 32 + n * 16 + lr;
            #pragma unroll
            for (int ks = 0; ks < 8; ++ks) {
                bf16x8 kf = *(const bf16x8*)(kl + srow * 512 + ((ks * 64 + lh * 16) ^ ((srow & 7) << 4)));
                sa = __builtin_amdgcn_mfma_f32_16x16x32_bf16(qf[0][ks], kf, sa, 0, 0, 0);
                sb = __builtin_amdgcn_mfma_f32_16x16x32_bf16(qf[1][ks], kf, sb, 0, 0, 0);
            }
            const int cb = (dh * 32 + n * 16 + lr) * 2;
            #pragma unroll
            for (int r = 0; r < 4; ++r) {
                float g0 = gbase[(long)(lh * 4 + r) * T_DIM + n * 16 + lr];
                float g1 = gbase[(long)(16 + lh * 4 + r) * T_DIM + n * 16 + lr];
                int pr0 = wq * 32 + lh * 4 + r;
                int pr1 = pr0 + 16;
                *(u16*)(pl + pr0 * 128 + (cb ^ ((pr0 & 7) << 4))) = f2bf(g0 * sa[r]);
                *(u16*)(pl + pr1 * 128 + (cb ^ ((pr1 & 7) << 4))) = f2bf(g1 * sb[r]);
            }
        }
        __syncthreads();                          // P tile complete (pair-shared)

        // PV: A = P rows (own 32), B = Vt rows (own 128 d-cols)
        bf16x8 pa[2][2];
        #pragma unroll
        for (int rg = 0; rg < 2; ++rg)
            #pragma unroll
            for (int k2 = 0; k2 < 2; ++k2) {
                int prr = wq * 32 + rg * 16 + lr;
                pa[rg][k2] = *(const bf16x8*)(pl + prr * 128 + ((k2 * 64 + lh * 16) ^ ((prr & 7) << 4)));
            }
        #pragma unroll
        for (int n = 0; n < 8; ++n) {
            int vrow = dh * 128 + n * 16 + lr;
            #pragma unroll
            for (int k2 = 0; k2 < 2; ++k2) {
                bf16x8 bv = *(const bf16x8*)(vl + vrow * 128 + ((k2 * 64 + lh * 16) ^ ((vrow & 7) << 4)));
                acc[0][n] = __builtin_amdgcn_mfma_f32_16x16x32_bf16(pa[0][k2], bv, acc[0][n], 0, 0, 0);
                acc[1][n] = __builtin_amdgcn_mfma_f32_16x16x32_bf16(pa[1][k2], bv, acc[1][n], 0, 0, 0);
            }
        }
    }

    // store R as bf16: rows q0+wq*32+rg*16+lh*4+r, cols dh*128+n*16+lr
    long grow = (long)b * T_DIM + q0 + wq * 32;
    #pragma unroll
    for (int rg = 0; rg < 2; ++rg)
        #pragma unroll
        for (int n = 0; n < 8; ++n) {
            int col = dh * 128 + n * 16 + lr;
            #pragma unroll
            for (int r = 0; r < 4; ++r) {
                int row = rg * 16 + lh * 4 + r;
                Rg[(grow + row) * DH + col] = f2bf(acc[rg][n][r]);
            }
        }
}

// ---------------- output projection + PReLU ----------------
__global__ __launch_bounds__(256) void out_kernel(
    const u16* __restrict__ Rg, const u16* __restrict__ Wot,
    const float* __restrict__ bo, const float* __restrict__ pa,
    float* __restrict__ out)
{
    __shared__ u16 rlds[64 * DH];
    char* rl = (char*)rlds;
    const int tid = threadIdx.x;
    const long row0 = (long)blockIdx.x * 64;
    #pragma unroll
    for (int i = 0; i < 8; ++i) {
        int sid = tid + i * 256;
        int row = sid >> 5, slot = sid & 31;
        u16x8 v = *(const u16x8*)((const char*)(Rg + (row0 + row) * DH) + slot * 16);
        *(u16x8*)(rl + row * 512 + ((slot * 16) ^ ((row & 7) << 4))) = v;
    }
    __syncthreads();
    const int w = tid >> 6, l = tid & 63;
    const int lr = l & 15, lh = l >> 4;
    const int arow = w * 16 + lr;
    f32x4 acc[16] = {};
    #pragma unroll
    for (int ks = 0; ks < 8; ++ks) {
        bf16x8 a = *(const bf16x8*)(rl + arow * 512 + ((ks * 64 + lh * 16) ^ ((arow & 7) << 4)));
        #pragma unroll
        for (int n = 0; n < 16; ++n) {
            bf16x8 bf = *(const bf16x8*)(Wot + (n * 16 + lr) * DH + ks * 32 + lh * 8);
            acc[n] = __builtin_amdgcn_mfma_f32_16x16x32_bf16(a, bf, acc[n], 0, 0, 0);
        }
    }
    const float alpha = pa[0];
    long grow = row0 + w * 16 + lh * 4;
    #pragma unroll
    for (int n = 0; n < 16; ++n) {
        int col = n * 16 + lr;
        float bb = bo[col];
        #pragma unroll
        for (int r = 0; r < 4; ++r) {
            float y = acc[n][r] + bb;
            out[(grow + r) * DH + col] = (y >= 0.f) ? y : alpha * y;
        }
    }
}

extern "C" void kernel_launch(void* const* d_in, const int* in_sizes, int n_in,
                              void* d_out, int out_size, void* d_ws, size_t ws_size,
                              hipStream_t stream)
{
    const float* x     = (const float*)d_in[0];
    const float* gamma = (const float*)d_in[1];
    const float* Wq = (const float*)d_in[2];
    const float* bq = (const float*)d_in[3];
    const float* Wk = (const float*)d_in[4];
    const float* bk = (const float*)d_in[5];
    const float* Wv = (const float*)d_in[6];
    const float* bv = (const float*)d_in[7];
    const float* Wo = (const float*)d_in[8];
    const float* bo = (const float*)d_in[9];
    const float* pa = (const float*)d_in[10];
    float* out = (float*)d_out;

    char* ws = (char*)d_ws;
    const long SZ = 16777216L;                 // 8*4096*256 bf16 bytes
    u16* Wqt = (u16*)(ws);
    u16* Wkt = (u16*)(ws + 131072);
    u16* Wvt = (u16*)(ws + 262144);
    u16* Wot = (u16*)(ws + 393216);
    u16* Qg  = (u16*)(ws + 524288);
    u16* Kg  = (u16*)(ws + 524288 + SZ);
    u16* Vtg = (u16*)(ws + 524288 + 2 * SZ);
    u16* Rg  = (u16*)(ws + 524288 + 3 * SZ);

    hipLaunchKernelGGL(prep_w, dim3(256), dim3(256), 0, stream,
                       Wq, Wk, Wv, Wo, Wqt, Wkt, Wvt, Wot);
    hipLaunchKernelGGL(qkv_kernel, dim3(512), dim3(256), 0, stream,
                       x, Wqt, Wkt, Wvt, bq, bk, bv, Qg, Kg, Vtg);
    hipLaunchKernelGGL(retention_kernel, dim3(256), dim3(512), 0, stream,
                       Qg, Kg, Vtg, gamma, Rg);
    hipLaunchKernelGGL(out_kernel, dim3(512), dim3(256), 0, stream,
                       Rg, Wot, bo, pa, out);
}

// Round 5
// 293.146 us; speedup vs baseline: 3.1612x; 1.1932x over previous
//
#include <hip/hip_runtime.h>

typedef unsigned short u16;
typedef __bf16 bf16x8 __attribute__((ext_vector_type(8)));
typedef float f32x4 __attribute__((ext_vector_type(4)));
typedef u16 u16x8 __attribute__((ext_vector_type(8)));

constexpr int T_DIM = 4096;
constexpr int DH    = 256;

__device__ __forceinline__ u16 f2bf(float f) {
    union { float f; unsigned u; } v; v.f = f;
    return (u16)((v.u + 0x7FFFu + ((v.u >> 16) & 1u)) >> 16);
}

// async global->LDS, 16B per lane; LDS dest = wave-uniform base + lane*16
__device__ __forceinline__ void gload_lds(const void* g, void* l) {
    __builtin_amdgcn_global_load_lds(
        (const __attribute__((address_space(1))) void*)g,
        (__attribute__((address_space(3))) void*)l, 16, 0, 0);
}

// ---------------- prep: Wt[j][k] = bf16(W[k][j]) ----------------
__global__ __launch_bounds__(256) void prep_w(
    const float* __restrict__ Wq, const float* __restrict__ Wk,
    const float* __restrict__ Wv, const float* __restrict__ Wo,
    u16* __restrict__ Wqt, u16* __restrict__ Wkt,
    u16* __restrict__ Wvt, u16* __restrict__ Wot)
{
    int idx = blockIdx.x * 256 + threadIdx.x;
    int j = idx >> 8, k = idx & 255;
    int s = k * 256 + j;
    Wqt[idx] = f2bf(Wq[s]);
    Wkt[idx] = f2bf(Wk[s]);
    Wvt[idx] = f2bf(Wv[s]);
    Wot[idx] = f2bf(Wo[s]);
}

// ---------------- QKV projection: 64 rows/block, 4 waves ----------------
__global__ __launch_bounds__(256) void qkv_kernel(
    const float* __restrict__ x,
    const u16* __restrict__ Wqt, const u16* __restrict__ Wkt, const u16* __restrict__ Wvt,
    const float* __restrict__ bq, const float* __restrict__ bk, const float* __restrict__ bv,
    u16* __restrict__ Qg, u16* __restrict__ Kg, u16* __restrict__ Vtg)
{
    __shared__ u16 xlds[64 * DH];          // 32KB; reused for V transpose at the end
    char* xl = (char*)xlds;
    const int tid = threadIdx.x;
    const long row0 = (long)blockIdx.x * 64;

    #pragma unroll
    for (int i = 0; i < 8; ++i) {
        int sid  = tid + i * 256;
        int row  = sid >> 5;
        int slot = sid & 31;
        const float* src = x + (row0 + row) * DH + slot * 8;
        float4 a  = *(const float4*)(src);
        float4 b2 = *(const float4*)(src + 4);
        u16x8 p;
        p[0] = f2bf(a.x);  p[1] = f2bf(a.y);  p[2] = f2bf(a.z);  p[3] = f2bf(a.w);
        p[4] = f2bf(b2.x); p[5] = f2bf(b2.y); p[6] = f2bf(b2.z); p[7] = f2bf(b2.w);
        *(u16x8*)(xl + row * 512 + ((slot * 16) ^ ((row & 7) << 4))) = p;
    }
    __syncthreads();

    const int w = tid >> 6, l = tid & 63;
    const int lr = l & 15, lh = l >> 4;
    const int arow = w * 16 + lr;

    bf16x8 af[8];
    #pragma unroll
    for (int ks = 0; ks < 8; ++ks)
        af[ks] = *(const bf16x8*)(xl + arow * 512 + ((ks * 64 + lh * 16) ^ ((arow & 7) << 4)));

    const u16*  Wt3[3] = { Wqt, Wkt, Wvt };
    const float* b3[3] = { bq, bk, bv };

    #pragma unroll
    for (int tgt = 0; tgt < 3; ++tgt) {
        f32x4 acc[16] = {};
        const u16* Wt = Wt3[tgt];
        #pragma unroll
        for (int ks = 0; ks < 8; ++ks) {
            bf16x8 a = af[ks];
            #pragma unroll
            for (int n = 0; n < 16; ++n) {
                bf16x8 bf = *(const bf16x8*)(Wt + (n * 16 + lr) * DH + ks * 32 + lh * 8);
                acc[n] = __builtin_amdgcn_mfma_f32_16x16x32_bf16(a, bf, acc[n], 0, 0, 0);
            }
        }
        const float* bias = b3[tgt];
        if (tgt < 2) {
            long grow = row0 + w * 16 + lh * 4;
            #pragma unroll
            for (int n = 0; n < 16; ++n) {
                int col = n * 16 + lr;
                float bb = bias[col];
                #pragma unroll
                for (int r = 0; r < 4; ++r) {
                    u16 h = f2bf(acc[n][r] + bb);
                    long g = grow + r;
                    if (tgt == 0) Qg[g * DH + col] = h;
                    else          Kg[g * DH + col] = h;
                }
            }
        } else {
            // V: transpose via LDS (xl is free), then coalesced u16x8 stores
            __syncthreads();
            #pragma unroll
            for (int n = 0; n < 16; ++n) {
                int col = n * 16 + lr;
                float bb = bias[col];
                #pragma unroll
                for (int r = 0; r < 4; ++r) {
                    int t = w * 16 + lh * 4 + r;
                    *(u16*)(xl + col * 128 + ((t * 2) ^ ((col & 7) << 4))) = f2bf(acc[n][r] + bb);
                }
            }
            __syncthreads();
            const long bb2 = row0 >> 12;             // batch
            const int  t0  = (int)(row0 & 4095);
            #pragma unroll
            for (int i = 0; i < 8; ++i) {
                int sid = tid + i * 256;
                int d = sid >> 3, slot = sid & 7;
                u16x8 v = *(const u16x8*)(xl + d * 128 + ((slot * 16) ^ ((d & 7) << 4)));
                *(u16x8*)((char*)Vtg + ((bb2 * DH + d) * T_DIM + t0) * 2 + slot * 16) = v;
            }
        }
    }
}

// ---- fused retention: 128 q-rows/block, 8 waves = 4 q-chunks x 2 d-halves ----
// double-buffered K/V tiles via global_load_lds (pre-swizzled source), 2 barriers/iter
__global__ __launch_bounds__(512, 2) void retention_kernel(
    const u16* __restrict__ Qg, const u16* __restrict__ Kg, const u16* __restrict__ Vtg,
    const float* __restrict__ gamma, u16* __restrict__ Rg)
{
    __shared__ __align__(16) char base[147456];   // buf0: K32K|V32K, buf1: K32K|V32K, P16K
    char* pl = base + 131072;
    const int tid = threadIdx.x;
    const int w = tid >> 6, l = tid & 63;
    const int lr = l & 15, lh = l >> 4;
    const int wq = w >> 1, dh = w & 1;            // q-chunk (32 rows), d-half (128 cols)
    const int b  = blockIdx.x >> 5;
    const int q0 = (blockIdx.x & 31) * 128;

    const char* kgb = (const char*)(Kg + (long)b * T_DIM * DH);        // batch K base
    const char* vgb = (const char*)Vtg + (long)b * DH * T_DIM * 2;     // batch Vt base

    // Q A-frags for the wave's 32 rows (persistent 64 VGPRs)
    bf16x8 qf[2][8];
    #pragma unroll
    for (int rg = 0; rg < 2; ++rg) {
        const char* qb = (const char*)(Qg + ((long)b * T_DIM + q0 + wq * 32 + rg * 16 + lr) * DH);
        #pragma unroll
        for (int ks = 0; ks < 8; ++ks)
            qf[rg][ks] = *(const bf16x8*)(qb + ks * 64 + lh * 16);
    }

    f32x4 acc[2][8] = {};                         // 32 rows x 128 cols -> 64 VGPRs

    // ---- prologue: stage tile 0 into buf0 ----
    {
        char* kn = base;
        #pragma unroll
        for (int i = 0; i < 4; ++i) {
            int off = w * 4096 + i * 1024 + l * 16;
            int row = off >> 9, slot = (off >> 4) & 31;
            gload_lds(kgb + row * 512 + ((slot * 16) ^ ((row & 7) << 4)),
                      kn + w * 4096 + i * 1024);
        }
        char* vn = base + 32768;
        #pragma unroll
        for (int i = 0; i < 4; ++i) {
            int off = w * 4096 + i * 1024 + l * 16;
            int row = off >> 7, slot = (off >> 4) & 7;
            gload_lds(vgb + (long)row * (T_DIM * 2) + ((slot * 16) ^ ((row & 7) << 4)),
                      vn + w * 4096 + i * 1024);
        }
    }
    __syncthreads();                              // vmcnt drained -> tile 0 ready

    for (int it = 0; it < 64; ++it) {
        const int s0 = it * 64;
        char* kl = base + (it & 1) * 65536;
        char* vl = kl + 32768;

        // 1. issue next tile's loads into the other buffer (in flight across this iter)
        if (it < 63) {
            const char* kg = kgb + (long)(s0 + 64) * 512;
            char* kn = base + ((it + 1) & 1) * 65536;
            #pragma unroll
            for (int i = 0; i < 4; ++i) {
                int off = w * 4096 + i * 1024 + l * 16;
                int row = off >> 9, slot = (off >> 4) & 31;
                gload_lds(kg + row * 512 + ((slot * 16) ^ ((row & 7) << 4)),
                          kn + w * 4096 + i * 1024);
            }
            const char* vg = vgb + (long)(s0 + 64) * 2;
            char* vn = kn + 32768;
            #pragma unroll
            for (int i = 0; i < 4; ++i) {
                int off = w * 4096 + i * 1024 + l * 16;
                int row = off >> 7, slot = (off >> 4) & 7;
                gload_lds(vg + (long)row * (T_DIM * 2) + ((slot * 16) ^ ((row & 7) << 4)),
                          vn + w * 4096 + i * 1024);
            }
        }

        // 2. gamma prefetch (consumed after QK^T MFMAs)
        float gv0[2][4], gv1[2][4];
        {
            const float* gbase = gamma + (long)(q0 + wq * 32) * T_DIM + s0 + dh * 32;
            #pragma unroll
            for (int n = 0; n < 2; ++n)
                #pragma unroll
                for (int r = 0; r < 4; ++r) {
                    gv0[n][r] = gbase[(long)(lh * 4 + r) * T_DIM + n * 16 + lr];
                    gv1[n][r] = gbase[(long)(16 + lh * 4 + r) * T_DIM + n * 16 + lr];
                }
        }

        // 3. QK^T: 32 q-rows x 32 s-cols (this wave's dh half), gate, pack, write P
        #pragma unroll
        for (int n = 0; n < 2; ++n) {
            f32x4 sa = {}, sb = {};
            const int srow = dh * 32 + n * 16 + lr;
            #pragma unroll
            for (int ks = 0; ks < 8; ++ks) {
                bf16x8 kf = *(const bf16x8*)(kl + srow * 512 + ((ks * 64 + lh * 16) ^ ((srow & 7) << 4)));
                sa = __builtin_amdgcn_mfma_f32_16x16x32_bf16(qf[0][ks], kf, sa, 0, 0, 0);
                sb = __builtin_amdgcn_mfma_f32_16x16x32_bf16(qf[1][ks], kf, sb, 0, 0, 0);
            }
            const int cb = (dh * 32 + n * 16 + lr) * 2;
            #pragma unroll
            for (int r = 0; r < 4; ++r) {
                int pr0 = wq * 32 + lh * 4 + r;
                int pr1 = pr0 + 16;
                *(u16*)(pl + pr0 * 128 + (cb ^ ((pr0 & 7) << 4))) = f2bf(gv0[n][r] * sa[r]);
                *(u16*)(pl + pr1 * 128 + (cb ^ ((pr1 & 7) << 4))) = f2bf(gv1[n][r] * sb[r]);
            }
        }
        __syncthreads();                          // P tile complete

        // 4. PV: A = P rows (own 32), B = Vt rows (own 128 d-cols)
        bf16x8 pa[2][2];
        #pragma unroll
        for (int rg = 0; rg < 2; ++rg)
            #pragma unroll
            for (int k2 = 0; k2 < 2; ++k2) {
                int prr = wq * 32 + rg * 16 + lr;
                pa[rg][k2] = *(const bf16x8*)(pl + prr * 128 + ((k2 * 64 + lh * 16) ^ ((prr & 7) << 4)));
            }
        #pragma unroll
        for (int n = 0; n < 8; ++n) {
            int vrow = dh * 128 + n * 16 + lr;
            #pragma unroll
            for (int k2 = 0; k2 < 2; ++k2) {
                bf16x8 bv = *(const bf16x8*)(vl + vrow * 128 + ((k2 * 64 + lh * 16) ^ ((vrow & 7) << 4)));
                acc[0][n] = __builtin_amdgcn_mfma_f32_16x16x32_bf16(pa[0][k2], bv, acc[0][n], 0, 0, 0);
                acc[1][n] = __builtin_amdgcn_mfma_f32_16x16x32_bf16(pa[1][k2], bv, acc[1][n], 0, 0, 0);
            }
        }
        __syncthreads();   // tile fully consumed; next-tile loads drained (vmcnt 0)
    }

    // store R as bf16
    long grow = (long)b * T_DIM + q0 + wq * 32;
    #pragma unroll
    for (int rg = 0; rg < 2; ++rg)
        #pragma unroll
        for (int n = 0; n < 8; ++n) {
            int col = dh * 128 + n * 16 + lr;
            #pragma unroll
            for (int r = 0; r < 4; ++r) {
                int row = rg * 16 + lh * 4 + r;
                Rg[(grow + row) * DH + col] = f2bf(acc[rg][n][r]);
            }
        }
}

// ---------------- output projection + PReLU ----------------
__global__ __launch_bounds__(256) void out_kernel(
    const u16* __restrict__ Rg, const u16* __restrict__ Wot,
    const float* __restrict__ bo, const float* __restrict__ pa,
    float* __restrict__ out)
{
    __shared__ u16 rlds[64 * DH];
    char* rl = (char*)rlds;
    const int tid = threadIdx.x;
    const long row0 = (long)blockIdx.x * 64;
    #pragma unroll
    for (int i = 0; i < 8; ++i) {
        int sid = tid + i * 256;
        int row = sid >> 5, slot = sid & 31;
        u16x8 v = *(const u16x8*)((const char*)(Rg + (row0 + row) * DH) + slot * 16);
        *(u16x8*)(rl + row * 512 + ((slot * 16) ^ ((row & 7) << 4))) = v;
    }
    __syncthreads();
    const int w = tid >> 6, l = tid & 63;
    const int lr = l & 15, lh = l >> 4;
    const int arow = w * 16 + lr;
    f32x4 acc[16] = {};
    #pragma unroll
    for (int ks = 0; ks < 8; ++ks) {
        bf16x8 a = *(const bf16x8*)(rl + arow * 512 + ((ks * 64 + lh * 16) ^ ((arow & 7) << 4)));
        #pragma unroll
        for (int n = 0; n < 16; ++n) {
            bf16x8 bf = *(const bf16x8*)(Wot + (n * 16 + lr) * DH + ks * 32 + lh * 8);
            acc[n] = __builtin_amdgcn_mfma_f32_16x16x32_bf16(a, bf, acc[n], 0, 0, 0);
        }
    }
    const float alpha = pa[0];
    long grow = row0 + w * 16 + lh * 4;
    #pragma unroll
    for (int n = 0; n < 16; ++n) {
        int col = n * 16 + lr;
        float bb = bo[col];
        #pragma unroll
        for (int r = 0; r < 4; ++r) {
            float y = acc[n][r] + bb;
            out[(grow + r) * DH + col] = (y >= 0.f) ? y : alpha * y;
        }
    }
}

extern "C" void kernel_launch(void* const* d_in, const int* in_sizes, int n_in,
                              void* d_out, int out_size, void* d_ws, size_t ws_size,
                              hipStream_t stream)
{
    const float* x     = (const float*)d_in[0];
    const float* gamma = (const float*)d_in[1];
    const float* Wq = (const float*)d_in[2];
    const float* bq = (const float*)d_in[3];
    const float* Wk = (const float*)d_in[4];
    const float* bk = (const float*)d_in[5];
    const float* Wv = (const float*)d_in[6];
    const float* bv = (const float*)d_in[7];
    const float* Wo = (const float*)d_in[8];
    const float* bo = (const float*)d_in[9];
    const float* pa = (const float*)d_in[10];
    float* out = (float*)d_out;

    char* ws = (char*)d_ws;
    const long SZ = 16777216L;                 // 8*4096*256 bf16 bytes
    u16* Wqt = (u16*)(ws);
    u16* Wkt = (u16*)(ws + 131072);
    u16* Wvt = (u16*)(ws + 262144);
    u16* Wot = (u16*)(ws + 393216);
    u16* Qg  = (u16*)(ws + 524288);
    u16* Kg  = (u16*)(ws + 524288 + SZ);
    u16* Vtg = (u16*)(ws + 524288 + 2 * SZ);
    u16* Rg  = (u16*)(ws + 524288 + 3 * SZ);

    hipLaunchKernelGGL(prep_w, dim3(256), dim3(256), 0, stream,
                       Wq, Wk, Wv, Wo, Wqt, Wkt, Wvt, Wot);
    hipLaunchKernelGGL(qkv_kernel, dim3(512), dim3(256), 0, stream,
                       x, Wqt, Wkt, Wvt, bq, bk, bv, Qg, Kg, Vtg);
    hipLaunchKernelGGL(retention_kernel, dim3(256), dim3(512), 0, stream,
                       Qg, Kg, Vtg, gamma, Rg);
    hipLaunchKernelGGL(out_kernel, dim3(512), dim3(256), 0, stream,
                       Rg, Wot, bo, pa, out);
}